// Round 3
// baseline (5263.559 us; speedup 1.0000x reference)
//
#include <hip/hip_runtime.h>

#define NA 512
#define NXX 512
#define MBATCH 64
#define TSTEPS 1024
#define MT (MBATCH * TSTEPS)       // 65536 flattened (m,t)
#define ASZ (NA * MBATCH * TSTEPS) // 33554432 elements per output tensor
#define PPC (NA * 16)              // per-chain ping-pong slice (floats)

typedef short bf16x8 __attribute__((ext_vector_type(8)));
typedef float f32x4 __attribute__((ext_vector_type(4)));

// Split fp32 -> bf16 hi + bf16 lo (3-term MFMA keeps error ~1e-3 << 2e-2).
__device__ __forceinline__ void split8(const float* v, bf16x8& h, bf16x8& l) {
#pragma unroll
  for (int j = 0; j < 8; ++j) {
    unsigned u = __float_as_uint(v[j]);
    unsigned short hb = (unsigned short)(u >> 16);
    float hf = __uint_as_float(((unsigned)hb) << 16);
    float rest = v[j] - hf;
    h[j] = (short)hb;
    l[j] = (short)(__float_as_uint(rest) >> 16);
  }
}

// C[n][mt] = W[n][k] @ S[k][mt] (+ bias[n]), n=512, k=512, mt=65536.
__global__ __launch_bounds__(256, 1) void wgemm(
    const float* __restrict__ W, const float* __restrict__ S,
    const float* __restrict__ bias, float* __restrict__ C) {
  const int tid = threadIdx.x;
  const int wv = tid >> 6;
  const int L = tid & 63;
  const int lo16 = L & 15;
  const int kq = L >> 4;
  const int n0 = blockIdx.y * 64;
  const int mt0 = blockIdx.x * 256 + wv * 64;

  f32x4 acc[4][4];
#pragma unroll
  for (int i = 0; i < 4; ++i)
#pragma unroll
    for (int j = 0; j < 4; ++j) acc[i][j] = (f32x4)0.0f;

  for (int kb = 0; kb < NXX; kb += 32) {
    const int ka = kb + kq * 8;
    bf16x8 Ah[4], Al[4], Bh[4], Bl[4];
#pragma unroll
    for (int i = 0; i < 4; ++i) {
      const float* p = W + (size_t)(n0 + i * 16 + lo16) * NXX + ka;
      float4 q0 = ((const float4*)p)[0];
      float4 q1 = ((const float4*)p)[1];
      float v[8] = {q0.x, q0.y, q0.z, q0.w, q1.x, q1.y, q1.z, q1.w};
      split8(v, Ah[i], Al[i]);
    }
#pragma unroll
    for (int j = 0; j < 4; ++j) {
      const int mt = mt0 + j * 16 + lo16;
      float v[8];
#pragma unroll
      for (int jj = 0; jj < 8; ++jj) v[jj] = S[(size_t)(ka + jj) * MT + mt];
      split8(v, Bh[j], Bl[j]);
    }
#pragma unroll
    for (int i = 0; i < 4; ++i)
#pragma unroll
      for (int j = 0; j < 4; ++j) {
        acc[i][j] = __builtin_amdgcn_mfma_f32_16x16x32_bf16(Ah[i], Bh[j], acc[i][j], 0, 0, 0);
        acc[i][j] = __builtin_amdgcn_mfma_f32_16x16x32_bf16(Ah[i], Bl[j], acc[i][j], 0, 0, 0);
        acc[i][j] = __builtin_amdgcn_mfma_f32_16x16x32_bf16(Al[i], Bh[j], acc[i][j], 0, 0, 0);
      }
  }
#pragma unroll
  for (int i = 0; i < 4; ++i) {
    const int nb = n0 + i * 16 + kq * 4;
#pragma unroll
    for (int r = 0; r < 4; ++r) {
      const float bv = bias ? bias[nb + r] : 0.0f;
#pragma unroll
      for (int j = 0; j < 4; ++j) {
        const int mt = mt0 + j * 16 + lo16;
        C[(size_t)(nb + r) * MT + mt] = acc[i][j][r] + bv;
      }
    }
  }
}

// Persistent scan. 32 WGs = 4 independent chains (m-groups of 16 cols) x 8
// row-groups. Chain-local epoch flags (no RMW), a exchanged through compact
// per-chain [k][16] fp32 ping-pong slices in ws via sc1 (agent) atomics.
//
// ROUND-2 DELTA vs the proven baseline: flags are per-WAVE (4 per WG), so
// the publish path is  {4 sc1 stores -> wave-local s_waitcnt vmcnt(0) ->
// lane-0 wave-flag}  with NO second __syncthreads. Producer wave (rg,wv)
// owns rows [64rg+16wv, +16) (rr = tid>>2 restricted to the wave's tids),
// so its own vmcnt(0) drain certifies exactly its 4 stores are LLC-acked —
// the WG-wide barrier added only a join on the slowest wave + a serialized
// tid0 flag store.
//
// SAFETY INVARIANT (same as baseline, finer grain): a wave's flag value t+1
// certifies that wave finished its step-t READS (the flag store issues
// after s_waitcnt vmcnt(0), which drains its B-loads and pp stores alike;
// reads precede publish in program order). Every consumer wave polls ALL 32
// chain wave-flags >= t before step t, so when anyone overwrites slot
// parity (t+1)&1 (holding a_{t-1}), every reader of a_{t-1} has provably
// finished. Two slots suffice. The dropped barrier is not needed for the
// LDS reduction either: red[] is double-buffered by t parity.
//
// Visibility: pp stores are sc1 write-through; vmcnt(0) means LLC-acked
// before the relaxed flag store. Consumer-side: agent-scope relaxed atomic
// loads read the LLC directly (proven by the flag poll observing remote
// stores while spinning) — only a compiler fence pins the pp loads after
// the poll (a HW acquire would force-flush partially-dirty Aout lines).
__global__ __launch_bounds__(256, 1) void scan_kernel(
    const float* __restrict__ Waa, const float* __restrict__ a0,
    const float* __restrict__ Z, float* __restrict__ Aout,
    float* __restrict__ pp, unsigned* __restrict__ flags) {
  const int tid = threadIdx.x;
  const int wv = tid >> 6;
  const int L = tid & 63;
  const int lo16 = L & 15;
  const int kq = L >> 4;
  const int wg = blockIdx.x;
  const int rg = wg >> 2;  // row-group within chain (8)
  const int mg = wg & 3;   // chain id
  const int n0 = rg * 64;
  const int m0 = mg * 16;
  const int kw = wv * 128;

  // Persistent split-bf16 A-fragments of the Waa slice.
  bf16x8 Ah[4][4], Al[4][4];
#pragma unroll
  for (int i = 0; i < 4; ++i)
#pragma unroll
    for (int s = 0; s < 4; ++s) {
      const float* p = Waa + (size_t)(n0 + i * 16 + lo16) * NA + kw + s * 32 + kq * 8;
      float4 q0 = ((const float4*)p)[0];
      float4 q1 = ((const float4*)p)[1];
      float v[8] = {q0.x, q0.y, q0.z, q0.w, q1.x, q1.y, q1.z, q1.w};
      split8(v, Ah[i][s], Al[i][s]);
    }

  __shared__ float red[2][4 * 64 * 17];  // double-buffered K-reduction

  const int rr = tid >> 2;  // output row within 64-row slice (wave wv: rows 16wv..16wv+15)
  const int mq = tid & 3;   // m-quad
  const size_t zb = ((size_t)(n0 + rr) * MBATCH + (m0 + mq * 4)) * TSTEPS;

  float* ppA = pp + (size_t)mg * PPC;            // buffer 0 slice
  float* ppB = pp + 4 * PPC + (size_t)mg * PPC;  // buffer 1 slice

  // 128 wave-flag slots x 32B: chain mg's wave W=(rg*4+wv) at slot mg*32+W.
  unsigned* pollf = flags + (size_t)(mg * 32 + (L & 31)) * 8;
  unsigned* mywf = flags + (size_t)(mg * 32 + rg * 4 + wv) * 8;

  float zv[4];
#pragma unroll
  for (int jj = 0; jj < 4; ++jj) zv[jj] = Z[zb + (size_t)jj * TSTEPS];

  for (int t = 0; t < TSTEPS; ++t) {
    if (t) {
      // Wait until every wave in this chain finished step t-1 (lanes 0..31
      // cover all 32 wave-flags; divergent loop exits when all are >= t).
      while (__hip_atomic_load(pollf, __ATOMIC_RELAXED, __HIP_MEMORY_SCOPE_AGENT) <
             (unsigned)t) {}
      __atomic_signal_fence(__ATOMIC_ACQUIRE);  // compiler-only: pin loads below
    }

    // B-fragments of a_{t-1}.
    const float* ap = (t == 0) ? a0 : ((t & 1) ? ppA : ppB);
    const int kst = (t == 0) ? MBATCH : 16;
    const int cof = (t == 0) ? (m0 + lo16) : lo16;
    bf16x8 Bh[4], Bl[4];
#pragma unroll
    for (int s = 0; s < 4; ++s) {
      const int k = kw + s * 32 + kq * 8;
      float v[8];
#pragma unroll
      for (int j = 0; j < 8; ++j)
        v[j] = __hip_atomic_load((const float*)(ap + (size_t)(k + j) * kst + cof),
                                 __ATOMIC_RELAXED, __HIP_MEMORY_SCOPE_AGENT);
      split8(v, Bh[s], Bl[s]);
    }

    f32x4 acc[4];
#pragma unroll
    for (int i = 0; i < 4; ++i) acc[i] = (f32x4)0.0f;
#pragma unroll
    for (int i = 0; i < 4; ++i)
#pragma unroll
      for (int s = 0; s < 4; ++s) {
        acc[i] = __builtin_amdgcn_mfma_f32_16x16x32_bf16(Ah[i][s], Bh[s], acc[i], 0, 0, 0);
        acc[i] = __builtin_amdgcn_mfma_f32_16x16x32_bf16(Ah[i][s], Bl[s], acc[i], 0, 0, 0);
        acc[i] = __builtin_amdgcn_mfma_f32_16x16x32_bf16(Al[i][s], Bh[s], acc[i], 0, 0, 0);
      }

    // Cross-wave K reduction (double-buffered; one barrier between wr/rd).
    float* rb = red[t & 1];
#pragma unroll
    for (int i = 0; i < 4; ++i)
#pragma unroll
      for (int r = 0; r < 4; ++r)
        rb[(wv * 64 + i * 16 + kq * 4 + r) * 17 + lo16] = acc[i][r];
    __syncthreads();

    float av[4];
#pragma unroll
    for (int jj = 0; jj < 4; ++jj) {
      const int m = mq * 4 + jj;
      float z = zv[jj];
#pragma unroll
      for (int w = 0; w < 4; ++w) z += rb[(w * 64 + rr) * 17 + m];
      const float e = __expf(z + z);  // e^{2z}; saturates correctly at +/-inf
      av[jj] = 1.0f - 2.0f / (e + 1.0f);
    }

    // Publish a_t for the chain: compact coalesced sc1 stores, then a
    // WAVE-local vmcnt(0) drain (stores LLC-acked) and the wave's flag.
    float* wb = (t & 1) ? ppB : ppA;
#pragma unroll
    for (int jj = 0; jj < 4; ++jj)
      __hip_atomic_store(wb + (size_t)(n0 + rr) * 16 + mq * 4 + jj, av[jj],
                         __ATOMIC_RELAXED, __HIP_MEMORY_SCOPE_AGENT);
    asm volatile("s_waitcnt vmcnt(0)" ::: "memory");
    if (L == 0) {
      __hip_atomic_store(mywf, (unsigned)(t + 1), __ATOMIC_RELAXED,
                         __HIP_MEMORY_SCOPE_AGENT);
    }

    // Off-critical-path: final strided output store (plain cached; lines fill
    // over 32 adjacent t's and write back lazily) + next-step Z prefetch.
#pragma unroll
    for (int jj = 0; jj < 4; ++jj)
      Aout[zb + (size_t)jj * TSTEPS + t] = av[jj];
    if (t + 1 < TSTEPS) {
#pragma unroll
      for (int jj = 0; jj < 4; ++jj) zv[jj] = Z[zb + (size_t)jj * TSTEPS + t + 1];
    }
  }
}

// Softmax over the batch axis m for each (n,t), in place.
__global__ __launch_bounds__(256, 2) void softmax_m(float* __restrict__ Y) {
  const int idx = blockIdx.x * 256 + threadIdx.x;
  const int n = idx >> 10;
  const int t = idx & 1023;
  float* base = Y + (size_t)n * MT + t;
  float v[64];
  float mx = -3.0e38f;
#pragma unroll
  for (int m = 0; m < 64; ++m) {
    v[m] = base[(size_t)m * TSTEPS];
    mx = fmaxf(mx, v[m]);
  }
  float s = 0.0f;
#pragma unroll
  for (int m = 0; m < 64; ++m) {
    v[m] = __expf(v[m] - mx);
    s += v[m];
  }
  const float inv = 1.0f / s;
#pragma unroll
  for (int m = 0; m < 64; ++m) base[(size_t)m * TSTEPS] = v[m] * inv;
}

extern "C" void kernel_launch(void* const* d_in, const int* in_sizes, int n_in,
                              void* d_out, int out_size, void* d_ws, size_t ws_size,
                              hipStream_t stream) {
  const float* x   = (const float*)d_in[0];
  const float* a0  = (const float*)d_in[1];
  const float* Waa = (const float*)d_in[2];
  const float* Wax = (const float*)d_in[3];
  const float* Wya = (const float*)d_in[4];
  const float* ba  = (const float*)d_in[5];
  // by (d_in[6]) cancels under softmax over the batch axis.

  float* A = (float*)d_out;    // final a_next [n][m][t]
  float* Y = A + (size_t)ASZ;  // staging for Z, then logits/y [n][m][t]

  unsigned* flags = (unsigned*)d_ws;          // 128 x 32B wave-flag slots (4 KB)
  float* pp = (float*)((char*)d_ws + 4096);   // 2 x 4 x PPC floats (256 KB)

  hipMemsetAsync(d_ws, 0, 4096, stream);

  // Phase 1: Z = Wax @ X + ba  -> Y region (read-only input for the scan)
  wgemm<<<dim3(256, 8), 256, 0, stream>>>(Wax, x, ba, Y);

  // Phase 2: a_t = tanh(Waa@a_{t-1} + Z_t) -> A region
  {
    void* args[] = {(void*)&Waa, (void*)&a0, (void*)&Y, (void*)&A,
                    (void*)&pp, (void*)&flags};
    hipLaunchCooperativeKernel((const void*)scan_kernel, dim3(32), dim3(256),
                               args, 0, stream);
  }

  // Phase 3: logits = Wya @ A -> Y region (overwrites Z, which is dead)
  wgemm<<<dim3(256, 8), 256, 0, stream>>>(Wya, A, (const float*)nullptr, Y);

  // Phase 4: softmax over batch axis, in place.
  softmax_m<<<2048, 256, 0, stream>>>(Y);
}

// Round 4
// 4466.158 us; speedup vs baseline: 1.1785x; 1.1785x over previous
//
#include <hip/hip_runtime.h>

#define NA 512
#define NXX 512
#define MBATCH 64
#define TSTEPS 1024
#define MT (MBATCH * TSTEPS)       // 65536 flattened (m,t)
#define ASZ (NA * MBATCH * TSTEPS) // 33554432 elements per output tensor
#define PPC (NA * 16)              // per-chain ping-pong slice (floats)

typedef short bf16x8 __attribute__((ext_vector_type(8)));
typedef float f32x4 __attribute__((ext_vector_type(4)));

// Split fp32 -> bf16 hi + bf16 lo (3-term MFMA keeps error ~1e-3 << 2e-2).
__device__ __forceinline__ void split8(const float* v, bf16x8& h, bf16x8& l) {
#pragma unroll
  for (int j = 0; j < 8; ++j) {
    unsigned u = __float_as_uint(v[j]);
    unsigned short hb = (unsigned short)(u >> 16);
    float hf = __uint_as_float(((unsigned)hb) << 16);
    float rest = v[j] - hf;
    h[j] = (short)hb;
    l[j] = (short)(__float_as_uint(rest) >> 16);
  }
}

// C[n][mt] = W[n][k] @ S[k][mt] (+ bias[n]), n=512, k=512, mt=65536.
__global__ __launch_bounds__(256, 1) void wgemm(
    const float* __restrict__ W, const float* __restrict__ S,
    const float* __restrict__ bias, float* __restrict__ C) {
  const int tid = threadIdx.x;
  const int wv = tid >> 6;
  const int L = tid & 63;
  const int lo16 = L & 15;
  const int kq = L >> 4;
  const int n0 = blockIdx.y * 64;
  const int mt0 = blockIdx.x * 256 + wv * 64;

  f32x4 acc[4][4];
#pragma unroll
  for (int i = 0; i < 4; ++i)
#pragma unroll
    for (int j = 0; j < 4; ++j) acc[i][j] = (f32x4)0.0f;

  for (int kb = 0; kb < NXX; kb += 32) {
    const int ka = kb + kq * 8;
    bf16x8 Ah[4], Al[4], Bh[4], Bl[4];
#pragma unroll
    for (int i = 0; i < 4; ++i) {
      const float* p = W + (size_t)(n0 + i * 16 + lo16) * NXX + ka;
      float4 q0 = ((const float4*)p)[0];
      float4 q1 = ((const float4*)p)[1];
      float v[8] = {q0.x, q0.y, q0.z, q0.w, q1.x, q1.y, q1.z, q1.w};
      split8(v, Ah[i], Al[i]);
    }
#pragma unroll
    for (int j = 0; j < 4; ++j) {
      const int mt = mt0 + j * 16 + lo16;
      float v[8];
#pragma unroll
      for (int jj = 0; jj < 8; ++jj) v[jj] = S[(size_t)(ka + jj) * MT + mt];
      split8(v, Bh[j], Bl[j]);
    }
#pragma unroll
    for (int i = 0; i < 4; ++i)
#pragma unroll
      for (int j = 0; j < 4; ++j) {
        acc[i][j] = __builtin_amdgcn_mfma_f32_16x16x32_bf16(Ah[i], Bh[j], acc[i][j], 0, 0, 0);
        acc[i][j] = __builtin_amdgcn_mfma_f32_16x16x32_bf16(Ah[i], Bl[j], acc[i][j], 0, 0, 0);
        acc[i][j] = __builtin_amdgcn_mfma_f32_16x16x32_bf16(Al[i], Bh[j], acc[i][j], 0, 0, 0);
      }
  }
#pragma unroll
  for (int i = 0; i < 4; ++i) {
    const int nb = n0 + i * 16 + kq * 4;
#pragma unroll
    for (int r = 0; r < 4; ++r) {
      const float bv = bias ? bias[nb + r] : 0.0f;
#pragma unroll
      for (int j = 0; j < 4; ++j) {
        const int mt = mt0 + j * 16 + lo16;
        C[(size_t)(nb + r) * MT + mt] = acc[i][j][r] + bv;
      }
    }
  }
}

// Persistent scan. 32 WGs = 4 independent chains (m-groups of 16 cols) x 8
// row-groups. Chain-local 8-flag epoch barrier (no RMW). a exchanged through
// compact per-chain [k][16] ping-pong slices in ws via sc1 (agent) atomics.
//
// PROVEN VERSION (3732 us) — byte-identical revert. Round-2's wave-granular
// flags regressed (+800 us): 32 polled flag lines across 16 sectors raised
// the expected poll-sampling misses (each ~700 cy LLC round trip), and the
// per-wave vmcnt(0) drain published no earlier than the barrier did.
//
// SAFETY INVARIANT (why 2 slots suffice): a WG's flag value t+1 certifies
// that WG finished its step-t READS (reads precede publish in program order,
// separated by __syncthreads). Every WG polls ALL 8 chain flags >= t before
// step t, so when anyone overwrites slot parity (t+1)&1 (holding a_{t-1}),
// every reader of a_{t-1} has provably finished.
//
// Visibility: pp stores are sc1 write-through; the publish __syncthreads
// drains each wave's vmcnt(0), so all pp data is LLC-acked before tid0's
// relaxed flag store. Consumer-side: agent-scope relaxed atomic loads read
// the LLC directly (proven by the flag poll observing remote stores while
// spinning), so NO hardware acquire fence is needed — only a compiler fence
// pins the pp loads after the poll.
__global__ __launch_bounds__(256, 1) void scan_kernel(
    const float* __restrict__ Waa, const float* __restrict__ a0,
    const float* __restrict__ Z, float* __restrict__ Aout,
    float* __restrict__ pp, unsigned* __restrict__ flags) {
  const int tid = threadIdx.x;
  const int wv = tid >> 6;
  const int L = tid & 63;
  const int lo16 = L & 15;
  const int kq = L >> 4;
  const int wg = blockIdx.x;
  const int rg = wg >> 2;  // row-group within chain (8)
  const int mg = wg & 3;   // chain id
  const int n0 = rg * 64;
  const int m0 = mg * 16;
  const int kw = wv * 128;

  // Persistent split-bf16 A-fragments of the Waa slice.
  bf16x8 Ah[4][4], Al[4][4];
#pragma unroll
  for (int i = 0; i < 4; ++i)
#pragma unroll
    for (int s = 0; s < 4; ++s) {
      const float* p = Waa + (size_t)(n0 + i * 16 + lo16) * NA + kw + s * 32 + kq * 8;
      float4 q0 = ((const float4*)p)[0];
      float4 q1 = ((const float4*)p)[1];
      float v[8] = {q0.x, q0.y, q0.z, q0.w, q1.x, q1.y, q1.z, q1.w};
      split8(v, Ah[i][s], Al[i][s]);
    }

  __shared__ float red[2][4 * 64 * 17];  // double-buffered K-reduction

  const int rr = tid >> 2;  // output row within 64-row slice
  const int mq = tid & 3;   // m-quad
  const size_t zb = ((size_t)(n0 + rr) * MBATCH + (m0 + mq * 4)) * TSTEPS;

  float* ppA = pp + (size_t)mg * PPC;            // buffer 0 slice
  float* ppB = pp + 4 * PPC + (size_t)mg * PPC;  // buffer 1 slice

  unsigned* pollf = flags + (size_t)(mg * 8 + (L & 7)) * 16;  // 64B-strided slots
  unsigned* myf = flags + (size_t)(mg * 8 + rg) * 16;

  float zv[4];
#pragma unroll
  for (int jj = 0; jj < 4; ++jj) zv[jj] = Z[zb + (size_t)jj * TSTEPS];

  for (int t = 0; t < TSTEPS; ++t) {
    if (t) {
      // Wait until every row-group in this chain finished step t-1.
      while (__hip_atomic_load(pollf, __ATOMIC_RELAXED, __HIP_MEMORY_SCOPE_AGENT) <
             (unsigned)t) {}
      __atomic_signal_fence(__ATOMIC_ACQUIRE);  // compiler-only: pin loads below
    }

    // B-fragments of a_{t-1}.
    const float* ap = (t == 0) ? a0 : ((t & 1) ? ppA : ppB);
    const int kst = (t == 0) ? MBATCH : 16;
    const int cof = (t == 0) ? (m0 + lo16) : lo16;
    bf16x8 Bh[4], Bl[4];
#pragma unroll
    for (int s = 0; s < 4; ++s) {
      const int k = kw + s * 32 + kq * 8;
      float v[8];
#pragma unroll
      for (int j = 0; j < 8; ++j)
        v[j] = __hip_atomic_load((const float*)(ap + (size_t)(k + j) * kst + cof),
                                 __ATOMIC_RELAXED, __HIP_MEMORY_SCOPE_AGENT);
      split8(v, Bh[s], Bl[s]);
    }

    f32x4 acc[4];
#pragma unroll
    for (int i = 0; i < 4; ++i) acc[i] = (f32x4)0.0f;
#pragma unroll
    for (int i = 0; i < 4; ++i)
#pragma unroll
      for (int s = 0; s < 4; ++s) {
        acc[i] = __builtin_amdgcn_mfma_f32_16x16x32_bf16(Ah[i][s], Bh[s], acc[i], 0, 0, 0);
        acc[i] = __builtin_amdgcn_mfma_f32_16x16x32_bf16(Ah[i][s], Bl[s], acc[i], 0, 0, 0);
        acc[i] = __builtin_amdgcn_mfma_f32_16x16x32_bf16(Al[i][s], Bh[s], acc[i], 0, 0, 0);
      }

    // Cross-wave K reduction (double-buffered; one barrier between wr/rd).
    float* rb = red[t & 1];
#pragma unroll
    for (int i = 0; i < 4; ++i)
#pragma unroll
      for (int r = 0; r < 4; ++r)
        rb[(wv * 64 + i * 16 + kq * 4 + r) * 17 + lo16] = acc[i][r];
    __syncthreads();

    float av[4];
#pragma unroll
    for (int jj = 0; jj < 4; ++jj) {
      const int m = mq * 4 + jj;
      float z = zv[jj];
#pragma unroll
      for (int w = 0; w < 4; ++w) z += rb[(w * 64 + rr) * 17 + m];
      const float e = __expf(z + z);  // e^{2z}; saturates correctly at +/-inf
      av[jj] = 1.0f - 2.0f / (e + 1.0f);
    }

    // Publish a_t for the chain: compact coalesced sc1 stores.
    float* wb = (t & 1) ? ppB : ppA;
#pragma unroll
    for (int jj = 0; jj < 4; ++jj)
      __hip_atomic_store(wb + (size_t)(n0 + rr) * 16 + mq * 4 + jj, av[jj],
                         __ATOMIC_RELAXED, __HIP_MEMORY_SCOPE_AGENT);
    __syncthreads();  // vmcnt(0) drain per wave: all pp stores are LLC-acked
    if (tid == 0) {
      __hip_atomic_store(myf, (unsigned)(t + 1), __ATOMIC_RELAXED,
                         __HIP_MEMORY_SCOPE_AGENT);
    }

    // Off-critical-path: final strided output store (plain cached; lines fill
    // over 32 adjacent t's and write back lazily) + next-step Z prefetch.
#pragma unroll
    for (int jj = 0; jj < 4; ++jj)
      Aout[zb + (size_t)jj * TSTEPS + t] = av[jj];
    if (t + 1 < TSTEPS) {
#pragma unroll
      for (int jj = 0; jj < 4; ++jj) zv[jj] = Z[zb + (size_t)jj * TSTEPS + t + 1];
    }
  }
}

// Softmax over the batch axis m for each (n,t), tiled through LDS.
// Old version read/wrote 64 dwords per (n,t) at 4KB stride — one 64B sector
// touched per dword, ~8x overfetch. New: block = (n, 256-wide t-tile);
// coalesced row loads (lane i -> t0+i) into a 64x256 LDS tile; each thread
// then owns one t-column and reduces over m (LDS column access is
// bank-uniform per instruction -> 2 lanes/bank, free); coalesced write-back.
__global__ __launch_bounds__(256, 2) void softmax_t(float* __restrict__ Y) {
  __shared__ float tile[64][256];  // 64 KB
  const int n = blockIdx.x >> 2;
  const int t0 = (blockIdx.x & 3) << 8;
  const int tid = threadIdx.x;
  float* base = Y + (size_t)n * MT + t0;

#pragma unroll
  for (int r = 0; r < 64; ++r)
    tile[r][tid] = base[(size_t)r * TSTEPS + tid];
  __syncthreads();

  float v[64];
  float mx = -3.0e38f;
#pragma unroll
  for (int m = 0; m < 64; ++m) {
    v[m] = tile[m][tid];
    mx = fmaxf(mx, v[m]);
  }
  float s = 0.0f;
#pragma unroll
  for (int m = 0; m < 64; ++m) {
    v[m] = __expf(v[m] - mx);
    s += v[m];
  }
  const float inv = 1.0f / s;
#pragma unroll
  for (int m = 0; m < 64; ++m) tile[m][tid] = v[m] * inv;
  __syncthreads();

#pragma unroll
  for (int r = 0; r < 64; ++r)
    base[(size_t)r * TSTEPS + tid] = tile[r][tid];
}

extern "C" void kernel_launch(void* const* d_in, const int* in_sizes, int n_in,
                              void* d_out, int out_size, void* d_ws, size_t ws_size,
                              hipStream_t stream) {
  const float* x   = (const float*)d_in[0];
  const float* a0  = (const float*)d_in[1];
  const float* Waa = (const float*)d_in[2];
  const float* Wax = (const float*)d_in[3];
  const float* Wya = (const float*)d_in[4];
  const float* ba  = (const float*)d_in[5];
  // by (d_in[6]) cancels under softmax over the batch axis.

  float* A = (float*)d_out;    // final a_next [n][m][t]
  float* Y = A + (size_t)ASZ;  // staging for Z, then logits/y [n][m][t]

  unsigned* flags = (unsigned*)d_ws;          // 32 x 64B epoch slots
  float* pp = (float*)((char*)d_ws + 4096);   // 2 x 4 x PPC floats (256 KB)

  hipMemsetAsync(d_ws, 0, 4096, stream);

  // Phase 1: Z = Wax @ X + ba  -> Y region (read-only input for the scan)
  wgemm<<<dim3(256, 8), 256, 0, stream>>>(Wax, x, ba, Y);

  // Phase 2: a_t = tanh(Waa@a_{t-1} + Z_t) -> A region
  {
    void* args[] = {(void*)&Waa, (void*)&a0, (void*)&Y, (void*)&A,
                    (void*)&pp, (void*)&flags};
    hipLaunchCooperativeKernel((const void*)scan_kernel, dim3(32), dim3(256),
                               args, 0, stream);
  }

  // Phase 3: logits = Wya @ A -> Y region (overwrites Z, which is dead)
  wgemm<<<dim3(256, 8), 256, 0, stream>>>(Wya, A, (const float*)nullptr, Y);

  // Phase 4: softmax over batch axis, tiled/coalesced, in place.
  softmax_t<<<2048, 256, 0, stream>>>(Y);
}

// Round 6
// 4430.539 us; speedup vs baseline: 1.1880x; 1.0080x over previous
//
#include <hip/hip_runtime.h>

#define NA 512
#define NXX 512
#define MBATCH 64
#define TSTEPS 1024
#define MT (MBATCH * TSTEPS)       // 65536 flattened (m,t)
#define ASZ (NA * MBATCH * TSTEPS) // 33554432 elements per output tensor
#define PPC (NA * 16)              // per-chain ping-pong slice (floats)

typedef short bf16x8 __attribute__((ext_vector_type(8)));
typedef float f32x4 __attribute__((ext_vector_type(4)));

// Split fp32 -> bf16 hi + bf16 lo (3-term MFMA keeps error ~1e-3 << 2e-2).
__device__ __forceinline__ void split8(const float* v, bf16x8& h, bf16x8& l) {
#pragma unroll
  for (int j = 0; j < 8; ++j) {
    unsigned u = __float_as_uint(v[j]);
    unsigned short hb = (unsigned short)(u >> 16);
    float hf = __uint_as_float(((unsigned)hb) << 16);
    float rest = v[j] - hf;
    h[j] = (short)hb;
    l[j] = (short)(__float_as_uint(rest) >> 16);
  }
}

// C[n][mt] = W[n][k] @ S[k][mt] (+ bias[n]), n=512, k=512, mt=65536.
__global__ __launch_bounds__(256, 1) void wgemm(
    const float* __restrict__ W, const float* __restrict__ S,
    const float* __restrict__ bias, float* __restrict__ C) {
  const int tid = threadIdx.x;
  const int wv = tid >> 6;
  const int L = tid & 63;
  const int lo16 = L & 15;
  const int kq = L >> 4;
  const int n0 = blockIdx.y * 64;
  const int mt0 = blockIdx.x * 256 + wv * 64;

  f32x4 acc[4][4];
#pragma unroll
  for (int i = 0; i < 4; ++i)
#pragma unroll
    for (int j = 0; j < 4; ++j) acc[i][j] = (f32x4)0.0f;

  for (int kb = 0; kb < NXX; kb += 32) {
    const int ka = kb + kq * 8;
    bf16x8 Ah[4], Al[4], Bh[4], Bl[4];
#pragma unroll
    for (int i = 0; i < 4; ++i) {
      const float* p = W + (size_t)(n0 + i * 16 + lo16) * NXX + ka;
      float4 q0 = ((const float4*)p)[0];
      float4 q1 = ((const float4*)p)[1];
      float v[8] = {q0.x, q0.y, q0.z, q0.w, q1.x, q1.y, q1.z, q1.w};
      split8(v, Ah[i], Al[i]);
    }
#pragma unroll
    for (int j = 0; j < 4; ++j) {
      const int mt = mt0 + j * 16 + lo16;
      float v[8];
#pragma unroll
      for (int jj = 0; jj < 8; ++jj) v[jj] = S[(size_t)(ka + jj) * MT + mt];
      split8(v, Bh[j], Bl[j]);
    }
#pragma unroll
    for (int i = 0; i < 4; ++i)
#pragma unroll
      for (int j = 0; j < 4; ++j) {
        acc[i][j] = __builtin_amdgcn_mfma_f32_16x16x32_bf16(Ah[i], Bh[j], acc[i][j], 0, 0, 0);
        acc[i][j] = __builtin_amdgcn_mfma_f32_16x16x32_bf16(Ah[i], Bl[j], acc[i][j], 0, 0, 0);
        acc[i][j] = __builtin_amdgcn_mfma_f32_16x16x32_bf16(Al[i], Bh[j], acc[i][j], 0, 0, 0);
      }
  }
#pragma unroll
  for (int i = 0; i < 4; ++i) {
    const int nb = n0 + i * 16 + kq * 4;
#pragma unroll
    for (int r = 0; r < 4; ++r) {
      const float bv = bias ? bias[nb + r] : 0.0f;
#pragma unroll
      for (int j = 0; j < 4; ++j) {
        const int mt = mt0 + j * 16 + lo16;
        C[(size_t)(nb + r) * MT + mt] = acc[i][j][r] + bv;
      }
    }
  }
}

// Persistent scan. 32 WGs = 4 independent chains (m-groups of 16 cols) x 8
// row-groups. Chain-local epoch flags (no RMW). a exchanged through compact
// per-chain [k][16] fp32 ping-pong slices in ws via sc1 (agent) atomics.
//
// ROUND-5: byte-identical to the proven 3736us kernel EXCEPT the poll set
// (single-line delta). Wave wv reads only K-rows [128wv,128wv+128) of
// a_{t-1}, produced by exactly WGs rg=2wv,2wv+1 — so the step-start poll
// waits on just those 2 flags (even lanes poll 2wv, odd lanes 2wv+1).
// NOTE: the packed-bf16 pp payload is QUARANTINED — present in all three
// unexplained failures (r0/r1/r4 proposals), absent from all passes.
//
// SAFETY INVARIANT (why 2 slots still suffice): flag_X = t certifies WG X
// finished its step-(t-1) READS (reads precede publish in program order;
// the publish __syncthreads drains each wave's vmcnt(0) — loads included —
// before the flag store). Before any WG's publish store at step t
// (overwriting the slot holding a_{t-2}), its 4 waves have jointly
// verified all 8 chain flags >= t (union of {2wv,2wv+1} over wv=0..3),
// joined by the pre-publish LDS-reduction __syncthreads. So every reader
// of a_{t-2} has provably finished before it is overwritten.
//
// Visibility: pp stores are sc1 write-through; the publish __syncthreads
// drains each wave's vmcnt(0), so all pp data is LLC-acked before tid0's
// relaxed flag store. Consumer-side: agent-scope relaxed atomic loads read
// the LLC directly (proven by the flag poll observing remote stores while
// spinning) — only a compiler fence pins the pp loads after the poll.
__global__ __launch_bounds__(256, 1) void scan_kernel(
    const float* __restrict__ Waa, const float* __restrict__ a0,
    const float* __restrict__ Z, float* __restrict__ Aout,
    float* __restrict__ pp, unsigned* __restrict__ flags) {
  const int tid = threadIdx.x;
  const int wv = tid >> 6;
  const int L = tid & 63;
  const int lo16 = L & 15;
  const int kq = L >> 4;
  const int wg = blockIdx.x;
  const int rg = wg >> 2;  // row-group within chain (8)
  const int mg = wg & 3;   // chain id
  const int n0 = rg * 64;
  const int m0 = mg * 16;
  const int kw = wv * 128;

  // Persistent split-bf16 A-fragments of the Waa slice.
  bf16x8 Ah[4][4], Al[4][4];
#pragma unroll
  for (int i = 0; i < 4; ++i)
#pragma unroll
    for (int s = 0; s < 4; ++s) {
      const float* p = Waa + (size_t)(n0 + i * 16 + lo16) * NA + kw + s * 32 + kq * 8;
      float4 q0 = ((const float4*)p)[0];
      float4 q1 = ((const float4*)p)[1];
      float v[8] = {q0.x, q0.y, q0.z, q0.w, q1.x, q1.y, q1.z, q1.w};
      split8(v, Ah[i][s], Al[i][s]);
    }

  __shared__ float red[2][4 * 64 * 17];  // double-buffered K-reduction

  const int rr = tid >> 2;  // output row within 64-row slice
  const int mq = tid & 3;   // m-quad
  const size_t zb = ((size_t)(n0 + rr) * MBATCH + (m0 + mq * 4)) * TSTEPS;

  float* ppA = pp + (size_t)mg * PPC;            // buffer 0 slice
  float* ppB = pp + 4 * PPC + (size_t)mg * PPC;  // buffer 1 slice

  // ROUND-5 DELTA: wave wv's data producers are row-groups 2wv, 2wv+1.
  unsigned* pollf = flags + (size_t)(mg * 8 + 2 * wv + (L & 1)) * 16;
  unsigned* myf = flags + (size_t)(mg * 8 + rg) * 16;

  float zv[4];
#pragma unroll
  for (int jj = 0; jj < 4; ++jj) zv[jj] = Z[zb + (size_t)jj * TSTEPS];

  for (int t = 0; t < TSTEPS; ++t) {
    if (t) {
      // Wait until THIS WAVE's two producers finished step t-1 (all-8
      // coverage for overwrite safety: union over waves + the pre-publish
      // __syncthreads — see header comment).
      while (__hip_atomic_load(pollf, __ATOMIC_RELAXED, __HIP_MEMORY_SCOPE_AGENT) <
             (unsigned)t) {}
      __atomic_signal_fence(__ATOMIC_ACQUIRE);  // compiler-only: pin loads below
    }

    // B-fragments of a_{t-1}.
    const float* ap = (t == 0) ? a0 : ((t & 1) ? ppA : ppB);
    const int kst = (t == 0) ? MBATCH : 16;
    const int cof = (t == 0) ? (m0 + lo16) : lo16;
    bf16x8 Bh[4], Bl[4];
#pragma unroll
    for (int s = 0; s < 4; ++s) {
      const int k = kw + s * 32 + kq * 8;
      float v[8];
#pragma unroll
      for (int j = 0; j < 8; ++j)
        v[j] = __hip_atomic_load((const float*)(ap + (size_t)(k + j) * kst + cof),
                                 __ATOMIC_RELAXED, __HIP_MEMORY_SCOPE_AGENT);
      split8(v, Bh[s], Bl[s]);
    }

    f32x4 acc[4];
#pragma unroll
    for (int i = 0; i < 4; ++i) acc[i] = (f32x4)0.0f;
#pragma unroll
    for (int i = 0; i < 4; ++i)
#pragma unroll
      for (int s = 0; s < 4; ++s) {
        acc[i] = __builtin_amdgcn_mfma_f32_16x16x32_bf16(Ah[i][s], Bh[s], acc[i], 0, 0, 0);
        acc[i] = __builtin_amdgcn_mfma_f32_16x16x32_bf16(Ah[i][s], Bl[s], acc[i], 0, 0, 0);
        acc[i] = __builtin_amdgcn_mfma_f32_16x16x32_bf16(Al[i][s], Bh[s], acc[i], 0, 0, 0);
      }

    // Cross-wave K reduction (double-buffered; one barrier between wr/rd).
    // This barrier also completes the chain-wide all-8 flag join: each wave
    // verified its 2 producers >= t, so past this point the whole WG knows
    // all 8 flags >= t — publishing (overwriting a_{t-2}) is safe.
    float* rb = red[t & 1];
#pragma unroll
    for (int i = 0; i < 4; ++i)
#pragma unroll
      for (int r = 0; r < 4; ++r)
        rb[(wv * 64 + i * 16 + kq * 4 + r) * 17 + lo16] = acc[i][r];
    __syncthreads();

    float av[4];
#pragma unroll
    for (int jj = 0; jj < 4; ++jj) {
      const int m = mq * 4 + jj;
      float z = zv[jj];
#pragma unroll
      for (int w = 0; w < 4; ++w) z += rb[(w * 64 + rr) * 17 + m];
      const float e = __expf(z + z);  // e^{2z}; saturates correctly at +/-inf
      av[jj] = 1.0f - 2.0f / (e + 1.0f);
    }

    // Publish a_t for the chain: compact coalesced sc1 stores.
    float* wb = (t & 1) ? ppB : ppA;
#pragma unroll
    for (int jj = 0; jj < 4; ++jj)
      __hip_atomic_store(wb + (size_t)(n0 + rr) * 16 + mq * 4 + jj, av[jj],
                         __ATOMIC_RELAXED, __HIP_MEMORY_SCOPE_AGENT);
    __syncthreads();  // vmcnt(0) drain per wave: all pp stores are LLC-acked
    if (tid == 0) {
      __hip_atomic_store(myf, (unsigned)(t + 1), __ATOMIC_RELAXED,
                         __HIP_MEMORY_SCOPE_AGENT);
    }

    // Off-critical-path: final strided output store (plain cached; lines fill
    // over 32 adjacent t's and write back lazily) + next-step Z prefetch.
#pragma unroll
    for (int jj = 0; jj < 4; ++jj)
      Aout[zb + (size_t)jj * TSTEPS + t] = av[jj];
    if (t + 1 < TSTEPS) {
#pragma unroll
      for (int jj = 0; jj < 4; ++jj) zv[jj] = Z[zb + (size_t)jj * TSTEPS + t + 1];
    }
  }
}

// Softmax over the batch axis m for each (n,t), tiled through LDS.
__global__ __launch_bounds__(256, 2) void softmax_t(float* __restrict__ Y) {
  __shared__ float tile[64][256];  // 64 KB
  const int n = blockIdx.x >> 2;
  const int t0 = (blockIdx.x & 3) << 8;
  const int tid = threadIdx.x;
  float* base = Y + (size_t)n * MT + t0;

#pragma unroll
  for (int r = 0; r < 64; ++r)
    tile[r][tid] = base[(size_t)r * TSTEPS + tid];
  __syncthreads();

  float v[64];
  float mx = -3.0e38f;
#pragma unroll
  for (int m = 0; m < 64; ++m) {
    v[m] = tile[m][tid];
    mx = fmaxf(mx, v[m]);
  }
  float s = 0.0f;
#pragma unroll
  for (int m = 0; m < 64; ++m) {
    v[m] = __expf(v[m] - mx);
    s += v[m];
  }
  const float inv = 1.0f / s;
#pragma unroll
  for (int m = 0; m < 64; ++m) tile[m][tid] = v[m] * inv;
  __syncthreads();

#pragma unroll
  for (int r = 0; r < 64; ++r)
    base[(size_t)r * TSTEPS + tid] = tile[r][tid];
}

extern "C" void kernel_launch(void* const* d_in, const int* in_sizes, int n_in,
                              void* d_out, int out_size, void* d_ws, size_t ws_size,
                              hipStream_t stream) {
  const float* x   = (const float*)d_in[0];
  const float* a0  = (const float*)d_in[1];
  const float* Waa = (const float*)d_in[2];
  const float* Wax = (const float*)d_in[3];
  const float* Wya = (const float*)d_in[4];
  const float* ba  = (const float*)d_in[5];
  // by (d_in[6]) cancels under softmax over the batch axis.

  float* A = (float*)d_out;    // final a_next [n][m][t]
  float* Y = A + (size_t)ASZ;  // staging for Z, then logits/y [n][m][t]

  unsigned* flags = (unsigned*)d_ws;          // 32 x 64B epoch slots
  float* pp = (float*)((char*)d_ws + 4096);   // 2 x 4 x PPC floats (256 KB)

  hipMemsetAsync(d_ws, 0, 4096, stream);

  // Phase 1: Z = Wax @ X + ba  -> Y region (read-only input for the scan)
  wgemm<<<dim3(256, 8), 256, 0, stream>>>(Wax, x, ba, Y);

  // Phase 2: a_t = tanh(Waa@a_{t-1} + Z_t) -> A region
  {
    void* args[] = {(void*)&Waa, (void*)&a0, (void*)&Y, (void*)&A,
                    (void*)&pp, (void*)&flags};
    hipLaunchCooperativeKernel((const void*)scan_kernel, dim3(32), dim3(256),
                               args, 0, stream);
  }

  // Phase 3: logits = Wya @ A -> Y region (overwrites Z, which is dead)
  wgemm<<<dim3(256, 8), 256, 0, stream>>>(Wya, A, (const float*)nullptr, Y);

  // Phase 4: softmax over batch axis, tiled/coalesced, in place.
  softmax_t<<<2048, 256, 0, stream>>>(Y);
}